// Round 18
// baseline (706.054 us; speedup 1.0000x reference)
//
#include <hip/hip_runtime.h>
#include <math.h>

// DrBC: encoder -> 5x(aggregate ; gru_mfma) -> decoder(6-layer max + MFMA).
// FLAT [N][128] bf16, PRE-SCALED hd = dinv*h; GRU/decoder un-scale by rdinv.
// aggregate: 2 nodes/wave, dwordx2, processed in DEGREE-SORTED order (counting-sort
// permutation; pairs have equal degree -> no exec-mask waste; bit-identical results).

#define NTHREADS 256
#define SCAN_CHUNK 1024

typedef __attribute__((ext_vector_type(8))) short s16x8;
typedef __attribute__((ext_vector_type(4))) float f32x4;

union U8 { s16x8 v; ushort4 h[2]; int4 q; };

__device__ __forceinline__ unsigned short f2bf(float f) {
  union { float f; unsigned u; } x; x.f = f;
  unsigned u = x.u + 0x7FFFu + ((x.u >> 16) & 1u);  // RNE to bf16
  return (unsigned short)(u >> 16);
}
__device__ __forceinline__ float bf2f(unsigned short s) {
  union { unsigned u; float f; } x; x.u = ((unsigned)s) << 16;
  return x.f;
}
__device__ __forceinline__ float fast_sigmoid(float x) {
  return __builtin_amdgcn_rcpf(1.f + __expf(-x));
}
__device__ __forceinline__ float fast_tanh(float x) {
  return 1.f - 2.f * __builtin_amdgcn_rcpf(1.f + __expf(2.f * x));
}

// ---------------- CSR build ----------------

__global__ void count_deg(const int* __restrict__ col, int* deg, int E) {
  int e = blockIdx.x * NTHREADS + threadIdx.x;
  if (e < E) atomicAdd(&deg[col[e]], 1);
}

// partial sums for scan + dinv/rdinv + degree histogram (256 bins)
__global__ void block_reduce(const int* __restrict__ cnt, int* __restrict__ bsum,
                             float* __restrict__ dinv, float* __restrict__ rdinv,
                             int* __restrict__ hist, int n) {
  __shared__ int red[NTHREADS];
  int b = blockIdx.x, t = threadIdx.x;
  int base = b * SCAN_CHUNK + t * 4;
  int s = 0;
#pragma unroll
  for (int i = 0; i < 4; ++i) {
    int idx = base + i;
    if (idx < n) {
      int c = cnt[idx];
      s += c;
      dinv[idx] = rsqrtf((float)c + 1.0f);
      rdinv[idx] = sqrtf((float)c + 1.0f);
      atomicAdd(&hist[c > 255 ? 255 : c], 1);
    }
  }
  red[t] = s;
  __syncthreads();
  for (int off = NTHREADS / 2; off > 0; off >>= 1) {
    if (t < off) red[t] += red[t + off];
    __syncthreads();
  }
  if (t == 0) bsum[b] = red[0];
}

// 64 threads (1 wave); nb <= 64.
__global__ void scan_partials(const int* __restrict__ bsum, int* __restrict__ boff,
                              int* __restrict__ row_ptr_n, int nb) {
  int t = threadIdx.x;
  int s = (t < nb) ? bsum[t] : 0;
  int orig = s;
#pragma unroll
  for (int off = 1; off < 64; off <<= 1) {
    int v = __shfl_up(s, off);
    if (t >= off) s += v;
  }
  if (t < nb) boff[t] = s - orig;
  if (t == nb - 1) *row_ptr_n = s;
}

__global__ void scan_final(const int* __restrict__ cnt, const int* __restrict__ boff,
                           int* __restrict__ row_ptr, int* __restrict__ cursor, int n) {
  __shared__ int sums[NTHREADS];
  int b = blockIdx.x, t = threadIdx.x;
  int base = b * SCAN_CHUNK + t * 4;
  int v[4];
  int s = 0;
#pragma unroll
  for (int i = 0; i < 4; ++i) { int idx = base + i; v[i] = (idx < n) ? cnt[idx] : 0; s += v[i]; }
  sums[t] = s;
  __syncthreads();
  for (int off = 1; off < NTHREADS; off <<= 1) {
    int a = (t >= off) ? sums[t - off] : 0;
    __syncthreads();
    sums[t] += a;
    __syncthreads();
  }
  int run = boff[b] + sums[t] - s;
#pragma unroll
  for (int i = 0; i < 4; ++i) {
    int idx = base + i;
    if (idx < n) { row_ptr[idx] = run; cursor[idx] = run; }
    run += v[i];
  }
}

// exclusive scan of hist[256] -> bin cursors (one block of 256)
__global__ void hist_scan(const int* __restrict__ hist, int* __restrict__ bincur) {
  __shared__ int sums[256];
  int t = threadIdx.x;
  int v = hist[t];
  sums[t] = v;
  __syncthreads();
  for (int off = 1; off < 256; off <<= 1) {
    int a = (t >= off) ? sums[t - off] : 0;
    __syncthreads();
    sums[t] += a;
    __syncthreads();
  }
  bincur[t] = sums[t] - v;  // exclusive
}

// perm: nodes ordered by degree (counting sort; any order within a bin is fine)
__global__ void perm_scatter(const int* __restrict__ deg, int* bincur,
                             int* __restrict__ perm, int n) {
  int i = blockIdx.x * NTHREADS + threadIdx.x;
  if (i >= n) return;
  int d = deg[i]; if (d > 255) d = 255;
  int p = atomicAdd(&bincur[d], 1);
  perm[p] = i;
}

// scatter: src index only (weights fully factorized into prescaled state)
__global__ void scatter_edges(const int* __restrict__ row, const int* __restrict__ col,
                              int* cursor, int* __restrict__ src, int E) {
  int e = blockIdx.x * NTHREADS + threadIdx.x;
  if (e >= E) return;
  int r = row[e], c = col[e];
  int p = atomicAdd(&cursor[c], 1);
  src[p] = r;
}

// ---------------- weight packs (merged): MFMA B-fragment order, bf16 ----------------
// k-map sigma(e,lane) = 32*ks + (e&3) + 4*((lane>>4)&3) + 16*(e>>2); same map on the
// A side -> result invariant to sigma's exact correctness.

__global__ void pack_all(const float* __restrict__ w_ih, const float* __restrict__ w_hh,
                         const float* __restrict__ W_hid,
                         unsigned short* __restrict__ out, unsigned short* __restrict__ outd) {
  int idx = blockIdx.x * NTHREADS + threadIdx.x;
  if (idx < 491520) {
    int e = idx & 7;
    int lane = (idx >> 3) & 63;
    int ft = (idx >> 9) & 7;
    int v = idx >> 12;
    int g = v % 6;
    int u = v / 6;
    int ks = u & 3;
    int layer = u >> 2;
    int k = 32 * ks + (e & 3) + 4 * ((lane >> 4) & 3) + 16 * (e >> 2);
    int j = 16 * ft + (lane & 15);
    const float* src = (g < 3) ? w_ih : w_hh;
    int gate = g % 3;
    out[idx] = f2bf(src[(size_t)layer * 49152 + (size_t)(gate * 128 + j) * 128 + k]);
  } else if (idx < 491520 + 8192) {
    int id2 = idx - 491520;
    int e = id2 & 7;
    int lane = (id2 >> 3) & 63;
    int ft = (id2 >> 9) & 3;
    int ks = id2 >> 11;
    int k = 32 * ks + (e & 3) + 4 * ((lane >> 4) & 3) + 16 * (e >> 2);
    int j = 16 * ft + (lane & 15);
    outd[id2] = f2bf(W_hid[j * 128 + k]);
  }
}

// ---------------- encoder: hd0 = dinv * l2norm(relu(xW+b)) (flat bf16) ----------------

__global__ void encoder(const float* __restrict__ x, const float* __restrict__ W,
                        const float* __restrict__ b, const float* __restrict__ dinv,
                        unsigned short* __restrict__ hd, int n) {
  int node = blockIdx.x * 4 + (threadIdx.x >> 6);
  int lane = threadIdx.x & 63;
  if (node >= n) return;
  float x0 = x[node * 3 + 0], x1 = x[node * 3 + 1], x2 = x[node * 3 + 2];
  int j0 = lane, j1 = lane + 64;
  float v0 = fmaxf(fmaf(W[j0 * 3 + 2], x2, fmaf(W[j0 * 3 + 1], x1, fmaf(W[j0 * 3], x0, b[j0]))), 0.f);
  float v1 = fmaxf(fmaf(W[j1 * 3 + 2], x2, fmaf(W[j1 * 3 + 1], x1, fmaf(W[j1 * 3], x0, b[j1]))), 0.f);
  float ss = v0 * v0 + v1 * v1;
#pragma unroll
  for (int sh = 32; sh > 0; sh >>= 1) ss += __shfl_down(ss, sh);
  ss = __shfl(ss, 0);
  float sc = 1.0f / fmaxf(sqrtf(ss), 1e-12f);
  float dv = dinv[node];
  size_t base = (size_t)node * 128;
  hd[base + j0] = f2bf(v0 * sc * dv);
  hd[base + j1] = f2bf(v1 * sc * dv);
}

// ---------------- aggregation: degree-sorted, 2 nodes/wave, dwordx2 ----------------
// agg[c] = dinv[c] * sum_e hd[src_e]; node = perm[slot] (degree-paired halves).

__global__ void aggregate(const int* __restrict__ row_ptr, const int* __restrict__ src,
                          const int* __restrict__ perm,
                          const float* __restrict__ dinv, const unsigned short* __restrict__ hd,
                          unsigned short* __restrict__ aggb, int n) {
  int wv = threadIdx.x >> 6;
  int lane = threadIdx.x & 63;
  int half = lane >> 5;
  int li = lane & 31;
  int slot = blockIdx.x * 8 + wv * 2 + half;
  if (slot >= n) return;
  int node = perm[slot];
  const uint2* hw = (const uint2*)hd;   // row = 32 x 8B
  int pb = row_ptr[node], pe = row_ptr[node + 1];
  float a0[4] = {0.f, 0.f, 0.f, 0.f};
  float a1[4] = {0.f, 0.f, 0.f, 0.f};
  float a2[4] = {0.f, 0.f, 0.f, 0.f};
  float a3[4] = {0.f, 0.f, 0.f, 0.f};
  for (int p = pb; p < pe; p += 8) {
    uint2 u[8]; float w8[8];
#pragma unroll
    for (int i = 0; i < 8; ++i) {
      int q = p + i;
      int ok = q < pe;
      int s = src[ok ? q : pb];
      w8[i] = ok ? 1.f : 0.f;
      u[i] = hw[(size_t)s * 32 + li];
    }
#pragma unroll
    for (int i = 0; i < 8; ++i) {
      a0[i & 3] = fmaf(w8[i], bf2f((unsigned short)(u[i].x & 0xFFFFu)), a0[i & 3]);
      a1[i & 3] = fmaf(w8[i], bf2f((unsigned short)(u[i].x >> 16)), a1[i & 3]);
      a2[i & 3] = fmaf(w8[i], bf2f((unsigned short)(u[i].y & 0xFFFFu)), a2[i & 3]);
      a3[i & 3] = fmaf(w8[i], bf2f((unsigned short)(u[i].y >> 16)), a3[i & 3]);
    }
  }
  float dc = dinv[node];
  float s0 = ((a0[0] + a0[1]) + (a0[2] + a0[3])) * dc;
  float s1 = ((a1[0] + a1[1]) + (a1[2] + a1[3])) * dc;
  float s2 = ((a2[0] + a2[1]) + (a2[2] + a2[3])) * dc;
  float s3 = ((a3[0] + a3[1]) + (a3[2] + a3[3])) * dc;
  uint2 o;
  o.x = ((unsigned)f2bf(s1) << 16) | (unsigned)f2bf(s0);
  o.y = ((unsigned)f2bf(s3) << 16) | (unsigned)f2bf(s2);
  ((uint2*)(aggb + (size_t)node * 128))[li] = o;
}

// ---------------- GRU layer via MFMA (R16 measured-best: 1024 threads, 64 nodes) ----------------

__global__ __launch_bounds__(1024) void gru_mfma(
    const unsigned short* __restrict__ aggb, const unsigned short* __restrict__ hdc,
    unsigned short* __restrict__ hdn, const float* __restrict__ dinv,
    const float* __restrict__ rdinv,
    const int4* __restrict__ wpk, const float* __restrict__ bih,
    const float* __restrict__ bhh, int n) {
  __shared__ unsigned short aggS[64 * 132];
  __shared__ unsigned short hS[64 * 132];
  __shared__ float partS[64 * 8];
  __shared__ float scv[64];
  __shared__ float dS[64], rS[64];
  int tid = threadIdx.x;
  int base = blockIdx.x * 64;
  int w = tid >> 6, l = tid & 63;
  int mh = w & 1, fh = w >> 1;
  int lr = l & 15, lg = l >> 4;
  int jj = fh * 16 + lr;

  if (tid < 64) {
    int gr = base + tid; if (gr > n - 1) gr = n - 1;
    dS[tid] = dinv[gr];
    rS[tid] = rdinv[gr];
  }
#pragma unroll
  for (int rep = 0; rep < 2; ++rep) {
    int idx = tid + rep * 1024;
    int row = idx >> 5, c4 = idx & 31;
    int gr = base + row; if (gr > n - 1) gr = n - 1;
    ushort4 ua = *(const ushort4*)(aggb + (size_t)gr * 128 + c4 * 4);
    ushort4 uh = *(const ushort4*)(hdc + (size_t)gr * 128 + c4 * 4);
    *(ushort4*)&aggS[row * 132 + c4 * 4] = ua;
    *(ushort4*)&hS[row * 132 + c4 * 4] = uh;
  }
  __syncthreads();

  f32x4 acc[2][6];
#pragma unroll
  for (int mt = 0; mt < 2; ++mt)
#pragma unroll
    for (int g = 0; g < 6; ++g) { acc[mt][g][0] = 0.f; acc[mt][g][1] = 0.f; acc[mt][g][2] = 0.f; acc[mt][g][3] = 0.f; }

#pragma unroll
  for (int ks = 0; ks < 4; ++ks) {
    U8 fa[2], fhh[2];
#pragma unroll
    for (int mt = 0; mt < 2; ++mt) {
      int boff = (mh * 32 + mt * 16 + lr) * 132 + ks * 32 + lg * 4;
      fa[mt].h[0] = *(const ushort4*)&aggS[boff];
      fa[mt].h[1] = *(const ushort4*)&aggS[boff + 16];
      fhh[mt].h[0] = *(const ushort4*)&hS[boff];
      fhh[mt].h[1] = *(const ushort4*)&hS[boff + 16];
    }
#pragma unroll
    for (int g = 0; g < 6; ++g) {
      U8 bw; bw.q = wpk[((ks * 6 + g) * 8 + fh) * 64 + l];
      const U8& a0 = (g < 3) ? fa[0] : fhh[0];
      const U8& a1 = (g < 3) ? fa[1] : fhh[1];
      acc[0][g] = __builtin_amdgcn_mfma_f32_16x16x32_bf16(a0.v, bw.v, acc[0][g], 0, 0, 0);
      acc[1][g] = __builtin_amdgcn_mfma_f32_16x16x32_bf16(a1.v, bw.v, acc[1][g], 0, 0, 0);
    }
  }

  float br = bih[jj], bz = bih[128 + jj], bn = bih[256 + jj];
  float cr = bhh[jj], cz = bhh[128 + jj], cn = bhh[256 + jj];
  float hn_out[2][4];
#pragma unroll
  for (int mt = 0; mt < 2; ++mt)
#pragma unroll
    for (int e = 0; e < 4; ++e) {
      int row = mh * 32 + mt * 16 + lg * 4 + e;
      float rr = rS[row];
      float ir = acc[mt][0][e], iz = acc[mt][1][e], inn = acc[mt][2][e];
      float hr = acc[mt][3][e] * rr, hz = acc[mt][4][e] * rr, hnv = acc[mt][5][e] * rr;
      float r = fast_sigmoid(ir + hr + br + cr);
      float z = fast_sigmoid(iz + hz + bz + cz);
      float ng = fast_tanh(inn + bn + r * (hnv + cn));
      float hv = bf2f(hS[row * 132 + jj]) * rr;
      float hn = (1.f - z) * ng + z * hv;
      hn_out[mt][e] = hn;
      float p = hn * hn;
      p += __shfl_xor(p, 1);
      p += __shfl_xor(p, 2);
      p += __shfl_xor(p, 4);
      p += __shfl_xor(p, 8);
      if (lr == 0) partS[row * 8 + fh] = p;
    }
  __syncthreads();
  if (tid < 64) {
    float ss = 0.f;
#pragma unroll
    for (int f = 0; f < 8; ++f) ss += partS[tid * 8 + f];
    scv[tid] = rsqrtf(fmaxf(ss, 1e-24f));
  }
  __syncthreads();

#pragma unroll
  for (int mt = 0; mt < 2; ++mt)
#pragma unroll
    for (int e = 0; e < 4; ++e) {
      int row = mh * 32 + mt * 16 + lg * 4 + e;
      aggS[row * 132 + jj] = f2bf(hn_out[mt][e] * scv[row] * dS[row]);
    }
  __syncthreads();

#pragma unroll
  for (int rep = 0; rep < 2; ++rep) {
    int idx = tid + rep * 1024;
    int row = idx >> 5, c4 = idx & 31;
    int gr = base + row;
    if (gr < n) {
      ushort4 hv4 = *(const ushort4*)&aggS[row * 132 + c4 * 4];
      *(ushort4*)(hdn + (size_t)gr * 128 + c4 * 4) = hv4;
    }
  }
}

// ---------------- decoder: 6-layer hd-max staging + MFMA + rdinv un-scale ----------------

__global__ __launch_bounds__(256) void decoder_mfma(
    const unsigned short* __restrict__ h0, const unsigned short* __restrict__ h1,
    const unsigned short* __restrict__ h2, const unsigned short* __restrict__ h3,
    const unsigned short* __restrict__ h4, const unsigned short* __restrict__ h5,
    const float* __restrict__ rdinv,
    const int4* __restrict__ wdpk, const float* __restrict__ bh,
    const float* __restrict__ Wo, const float* __restrict__ bo,
    float* __restrict__ out, int n) {
  __shared__ unsigned short zS[64 * 132];
  int tid = threadIdx.x;
  int base = blockIdx.x * 64;
  const unsigned short* hp[6] = {h0, h1, h2, h3, h4, h5};
#pragma unroll
  for (int rep = 0; rep < 8; ++rep) {
    int idx = tid + rep * 256;
    int row = idx >> 5, c4 = idx & 31;
    int gr = base + row; if (gr > n - 1) gr = n - 1;
    size_t o = (size_t)gr * 128 + c4 * 4;
    ushort4 uu[6];
#pragma unroll
    for (int li = 0; li < 6; ++li) uu[li] = *(const ushort4*)(hp[li] + o);
    ushort4 m = uu[0];
#pragma unroll
    for (int li = 1; li < 6; ++li) {
      m.x = (bf2f(uu[li].x) > bf2f(m.x)) ? uu[li].x : m.x;
      m.y = (bf2f(uu[li].y) > bf2f(m.y)) ? uu[li].y : m.y;
      m.z = (bf2f(uu[li].z) > bf2f(m.z)) ? uu[li].z : m.z;
      m.w = (bf2f(uu[li].w) > bf2f(m.w)) ? uu[li].w : m.w;
    }
    *(ushort4*)&zS[row * 132 + c4 * 4] = m;
  }
  __syncthreads();
  int w = tid >> 6, l = tid & 63;
  int lr = l & 15, lg = l >> 4;
  f32x4 acc[4];
#pragma unroll
  for (int ft = 0; ft < 4; ++ft) { acc[ft][0] = 0.f; acc[ft][1] = 0.f; acc[ft][2] = 0.f; acc[ft][3] = 0.f; }
#pragma unroll
  for (int ks = 0; ks < 4; ++ks) {
    U8 fz;
    int boff = (w * 16 + lr) * 132 + ks * 32 + lg * 4;
    fz.h[0] = *(const ushort4*)&zS[boff];
    fz.h[1] = *(const ushort4*)&zS[boff + 16];
#pragma unroll
    for (int ft = 0; ft < 4; ++ft) {
      U8 bw; bw.q = wdpk[(ks * 4 + ft) * 64 + l];
      acc[ft] = __builtin_amdgcn_mfma_f32_16x16x32_bf16(fz.v, bw.v, acc[ft], 0, 0, 0);
    }
  }
  int rowb = base + w * 16 + lg * 4;
  float rr[4];
#pragma unroll
  for (int e = 0; e < 4; ++e) {
    int gr = rowb + e; if (gr > n - 1) gr = n - 1;
    rr[e] = rdinv[gr];
  }
  float s[4] = {0.f, 0.f, 0.f, 0.f};
#pragma unroll
  for (int ft = 0; ft < 4; ++ft) {
    int j = ft * 16 + lr;
    float bj = bh[j], wj = Wo[j];
#pragma unroll
    for (int e = 0; e < 4; ++e) {
      float hid = fmaxf(fmaf(acc[ft][e], rr[e], bj), 0.f);
      s[e] = fmaf(hid, wj, s[e]);
    }
  }
#pragma unroll
  for (int e = 0; e < 4; ++e) {
    float v = s[e];
    v += __shfl_xor(v, 1);
    v += __shfl_xor(v, 2);
    v += __shfl_xor(v, 4);
    v += __shfl_xor(v, 8);
    if (lr == 0) {
      int gr = rowb + e;
      if (gr < n) out[gr] = v + bo[0];
    }
  }
}

// ---------------- launch ----------------

extern "C" void kernel_launch(void* const* d_in, const int* in_sizes, int n_in,
                              void* d_out, int out_size, void* d_ws, size_t ws_size,
                              hipStream_t stream) {
  const float* x       = (const float*)d_in[0];
  const int*   edge    = (const int*)d_in[1];
  const float* W_embed = (const float*)d_in[2];
  const float* b_embed = (const float*)d_in[3];
  const float* w_ih    = (const float*)d_in[4];
  const float* w_hh    = (const float*)d_in[5];
  const float* b_ih    = (const float*)d_in[6];
  const float* b_hh    = (const float*)d_in[7];
  const float* W_hid   = (const float*)d_in[8];
  const float* b_hid   = (const float*)d_in[9];
  const float* W_out   = (const float*)d_in[10];
  const float* b_out   = (const float*)d_in[11];
  float* out = (float*)d_out;

  const int N = in_sizes[0] / 3;       // 50000
  const int E = in_sizes[1] / 2;       // 600000
  const int NB = (N + SCAN_CHUNK - 1) / SCAN_CHUNK;

  char* ws = (char*)d_ws;
  size_t off = 0;
  auto alloc = [&](size_t bytes) -> void* {
    void* p = ws + off;
    off = (off + bytes + 511) & ~(size_t)511;
    return p;
  };
  int*   deg     = (int*)alloc((size_t)(N + 256) * 4);   // deg[N] + hist[256] (one memset)
  int*   hist    = deg + N;
  float* dinv    = (float*)alloc((size_t)N * 4);
  float* rdinv   = (float*)alloc((size_t)N * 4);
  int*   row_ptr = (int*)alloc((size_t)(N + 1) * 4);
  int*   cursor  = (int*)alloc((size_t)N * 4);
  int*   bsum    = (int*)alloc((size_t)NB * 4);
  int*   boff    = (int*)alloc((size_t)NB * 4);
  int*   bincur  = (int*)alloc((size_t)256 * 4);
  int*   perm    = (int*)alloc((size_t)N * 4);
  int*   srcv    = (int*)alloc((size_t)(E + 8) * 4);
  unsigned short* wpack  = (unsigned short*)alloc((size_t)491520 * 2);
  unsigned short* wdpack = (unsigned short*)alloc((size_t)8192 * 2);
  unsigned short* aggb   = (unsigned short*)alloc((size_t)N * 128 * 2);
  unsigned short* hbs[6];
  for (int i = 0; i < 6; ++i) hbs[i] = (unsigned short*)alloc((size_t)N * 128 * 2);

  const int* erow = edge;
  const int* ecol = edge + E;

  hipMemsetAsync(deg, 0, (size_t)(N + 256) * 4, stream);
  count_deg<<<(E + NTHREADS - 1) / NTHREADS, NTHREADS, 0, stream>>>(ecol, deg, E);
  block_reduce<<<NB, NTHREADS, 0, stream>>>(deg, bsum, dinv, rdinv, hist, N);
  scan_partials<<<1, 64, 0, stream>>>(bsum, boff, row_ptr + N, NB);
  scan_final<<<NB, NTHREADS, 0, stream>>>(deg, boff, row_ptr, cursor, N);
  hist_scan<<<1, 256, 0, stream>>>(hist, bincur);
  perm_scatter<<<(N + NTHREADS - 1) / NTHREADS, NTHREADS, 0, stream>>>(deg, bincur, perm, N);
  scatter_edges<<<(E + NTHREADS - 1) / NTHREADS, NTHREADS, 0, stream>>>(erow, ecol, cursor, srcv, E);

  pack_all<<<(491520 + 8192 + NTHREADS - 1) / NTHREADS, NTHREADS, 0, stream>>>(
      w_ih, w_hh, W_hid, wpack, wdpack);

  encoder<<<(N + 3) / 4, NTHREADS, 0, stream>>>(x, W_embed, b_embed, dinv, hbs[0], N);

  for (int l = 0; l < 5; ++l) {
    aggregate<<<(N + 7) / 8, NTHREADS, 0, stream>>>(row_ptr, srcv, perm, dinv, hbs[l], aggb, N);
    gru_mfma<<<(N + 63) / 64, 1024, 0, stream>>>(
        aggb, hbs[l], hbs[l + 1], dinv, rdinv,
        (const int4*)(wpack + (size_t)l * 98304),
        b_ih + (size_t)l * 384, b_hh + (size_t)l * 384, N);
  }

  decoder_mfma<<<(N + 63) / 64, NTHREADS, 0, stream>>>(
      hbs[0], hbs[1], hbs[2], hbs[3], hbs[4], hbs[5], rdinv,
      (const int4*)wdpack, b_hid, W_out, b_out, out, N);
}

// Round 19
// 383.194 us; speedup vs baseline: 1.8425x; 1.8425x over previous
//
#include <hip/hip_runtime.h>
#include <math.h>

// DrBC: encoder -> 5x(aggregate ; gru_mfma) -> decoder(6-layer max + MFMA).
// FLAT [N][128] bf16, PRE-SCALED hd = dinv*h (aggregate = pure row-sum, no per-edge
// weights); GRU/decoder un-scale rows by rdinv = sqrt(deg+1). HW rcp/exp gate math.
// R16 measured-best config: aggregate 2 nodes/wave dwordx2; gru 1024 thr / 64 nodes.

#define NTHREADS 256
#define SCAN_CHUNK 1024

typedef __attribute__((ext_vector_type(8))) short s16x8;
typedef __attribute__((ext_vector_type(4))) float f32x4;

union U8 { s16x8 v; ushort4 h[2]; int4 q; };

__device__ __forceinline__ unsigned short f2bf(float f) {
  union { float f; unsigned u; } x; x.f = f;
  unsigned u = x.u + 0x7FFFu + ((x.u >> 16) & 1u);  // RNE to bf16
  return (unsigned short)(u >> 16);
}
__device__ __forceinline__ float bf2f(unsigned short s) {
  union { unsigned u; float f; } x; x.u = ((unsigned)s) << 16;
  return x.f;
}
__device__ __forceinline__ float fast_sigmoid(float x) {
  return __builtin_amdgcn_rcpf(1.f + __expf(-x));
}
__device__ __forceinline__ float fast_tanh(float x) {
  return 1.f - 2.f * __builtin_amdgcn_rcpf(1.f + __expf(2.f * x));
}

// ---------------- CSR build ----------------

__global__ void count_deg(const int* __restrict__ col, int* deg, int E) {
  int e = blockIdx.x * NTHREADS + threadIdx.x;
  if (e < E) atomicAdd(&deg[col[e]], 1);
}

__global__ void block_reduce(const int* __restrict__ cnt, int* __restrict__ bsum,
                             float* __restrict__ dinv, float* __restrict__ rdinv, int n) {
  __shared__ int red[NTHREADS];
  int b = blockIdx.x, t = threadIdx.x;
  int base = b * SCAN_CHUNK + t * 4;
  int s = 0;
#pragma unroll
  for (int i = 0; i < 4; ++i) {
    int idx = base + i;
    if (idx < n) {
      int c = cnt[idx];
      s += c;
      dinv[idx] = rsqrtf((float)c + 1.0f);
      rdinv[idx] = sqrtf((float)c + 1.0f);
    }
  }
  red[t] = s;
  __syncthreads();
  for (int off = NTHREADS / 2; off > 0; off >>= 1) {
    if (t < off) red[t] += red[t + off];
    __syncthreads();
  }
  if (t == 0) bsum[b] = red[0];
}

// 64 threads (1 wave); nb <= 64.
__global__ void scan_partials(const int* __restrict__ bsum, int* __restrict__ boff,
                              int* __restrict__ row_ptr_n, int nb) {
  int t = threadIdx.x;
  int s = (t < nb) ? bsum[t] : 0;
  int orig = s;
#pragma unroll
  for (int off = 1; off < 64; off <<= 1) {
    int v = __shfl_up(s, off);
    if (t >= off) s += v;
  }
  if (t < nb) boff[t] = s - orig;
  if (t == nb - 1) *row_ptr_n = s;
}

__global__ void scan_final(const int* __restrict__ cnt, const int* __restrict__ boff,
                           int* __restrict__ row_ptr, int* __restrict__ cursor, int n) {
  __shared__ int sums[NTHREADS];
  int b = blockIdx.x, t = threadIdx.x;
  int base = b * SCAN_CHUNK + t * 4;
  int v[4];
  int s = 0;
#pragma unroll
  for (int i = 0; i < 4; ++i) { int idx = base + i; v[i] = (idx < n) ? cnt[idx] : 0; s += v[i]; }
  sums[t] = s;
  __syncthreads();
  for (int off = 1; off < NTHREADS; off <<= 1) {
    int a = (t >= off) ? sums[t - off] : 0;
    __syncthreads();
    sums[t] += a;
    __syncthreads();
  }
  int run = boff[b] + sums[t] - s;
#pragma unroll
  for (int i = 0; i < 4; ++i) {
    int idx = base + i;
    if (idx < n) { row_ptr[idx] = run; cursor[idx] = run; }
    run += v[i];
  }
}

// scatter: src index only (weights fully factorized into prescaled state)
__global__ void scatter_edges(const int* __restrict__ row, const int* __restrict__ col,
                              int* cursor, int* __restrict__ src, int E) {
  int e = blockIdx.x * NTHREADS + threadIdx.x;
  if (e >= E) return;
  int r = row[e], c = col[e];
  int p = atomicAdd(&cursor[c], 1);
  src[p] = r;
}

// ---------------- weight packs (merged): MFMA B-fragment order, bf16 ----------------
// k-map sigma(e,lane) = 32*ks + (e&3) + 4*((lane>>4)&3) + 16*(e>>2); same map on the
// A side -> result invariant to sigma's exact correctness.

__global__ void pack_all(const float* __restrict__ w_ih, const float* __restrict__ w_hh,
                         const float* __restrict__ W_hid,
                         unsigned short* __restrict__ out, unsigned short* __restrict__ outd) {
  int idx = blockIdx.x * NTHREADS + threadIdx.x;
  if (idx < 491520) {
    int e = idx & 7;
    int lane = (idx >> 3) & 63;
    int ft = (idx >> 9) & 7;
    int v = idx >> 12;
    int g = v % 6;
    int u = v / 6;
    int ks = u & 3;
    int layer = u >> 2;
    int k = 32 * ks + (e & 3) + 4 * ((lane >> 4) & 3) + 16 * (e >> 2);
    int j = 16 * ft + (lane & 15);
    const float* src = (g < 3) ? w_ih : w_hh;
    int gate = g % 3;
    out[idx] = f2bf(src[(size_t)layer * 49152 + (size_t)(gate * 128 + j) * 128 + k]);
  } else if (idx < 491520 + 8192) {
    int id2 = idx - 491520;
    int e = id2 & 7;
    int lane = (id2 >> 3) & 63;
    int ft = (id2 >> 9) & 3;
    int ks = id2 >> 11;
    int k = 32 * ks + (e & 3) + 4 * ((lane >> 4) & 3) + 16 * (e >> 2);
    int j = 16 * ft + (lane & 15);
    outd[id2] = f2bf(W_hid[j * 128 + k]);
  }
}

// ---------------- encoder: hd0 = dinv * l2norm(relu(xW+b)) (flat bf16) ----------------

__global__ void encoder(const float* __restrict__ x, const float* __restrict__ W,
                        const float* __restrict__ b, const float* __restrict__ dinv,
                        unsigned short* __restrict__ hd, int n) {
  int node = blockIdx.x * 4 + (threadIdx.x >> 6);
  int lane = threadIdx.x & 63;
  if (node >= n) return;
  float x0 = x[node * 3 + 0], x1 = x[node * 3 + 1], x2 = x[node * 3 + 2];
  int j0 = lane, j1 = lane + 64;
  float v0 = fmaxf(fmaf(W[j0 * 3 + 2], x2, fmaf(W[j0 * 3 + 1], x1, fmaf(W[j0 * 3], x0, b[j0]))), 0.f);
  float v1 = fmaxf(fmaf(W[j1 * 3 + 2], x2, fmaf(W[j1 * 3 + 1], x1, fmaf(W[j1 * 3], x0, b[j1]))), 0.f);
  float ss = v0 * v0 + v1 * v1;
#pragma unroll
  for (int sh = 32; sh > 0; sh >>= 1) ss += __shfl_down(ss, sh);
  ss = __shfl(ss, 0);
  float sc = 1.0f / fmaxf(sqrtf(ss), 1e-12f);
  float dv = dinv[node];
  size_t base = (size_t)node * 128;
  hd[base + j0] = f2bf(v0 * sc * dv);
  hd[base + j1] = f2bf(v1 * sc * dv);
}

// ---------------- aggregation: 2 nodes/wave, dwordx2 gathers, 8-deep ----------------
// agg[c] = dinv[c] * sum_e hd[src_e]; wave = 2 x 32-lane halves, lane li owns 8B of row.

__global__ void aggregate(const int* __restrict__ row_ptr, const int* __restrict__ src,
                          const float* __restrict__ dinv, const unsigned short* __restrict__ hd,
                          unsigned short* __restrict__ aggb, int n) {
  int wv = threadIdx.x >> 6;
  int lane = threadIdx.x & 63;
  int half = lane >> 5;
  int li = lane & 31;
  int node = blockIdx.x * 8 + wv * 2 + half;
  if (node >= n) return;
  const uint2* hw = (const uint2*)hd;   // row = 32 x 8B
  int pb = row_ptr[node], pe = row_ptr[node + 1];
  float a0[4] = {0.f, 0.f, 0.f, 0.f};
  float a1[4] = {0.f, 0.f, 0.f, 0.f};
  float a2[4] = {0.f, 0.f, 0.f, 0.f};
  float a3[4] = {0.f, 0.f, 0.f, 0.f};
  for (int p = pb; p < pe; p += 8) {
    uint2 u[8]; float w8[8];
#pragma unroll
    for (int i = 0; i < 8; ++i) {
      int q = p + i;
      int ok = q < pe;
      int s = src[ok ? q : pb];
      w8[i] = ok ? 1.f : 0.f;
      u[i] = hw[(size_t)s * 32 + li];
    }
#pragma unroll
    for (int i = 0; i < 8; ++i) {
      a0[i & 3] = fmaf(w8[i], bf2f((unsigned short)(u[i].x & 0xFFFFu)), a0[i & 3]);
      a1[i & 3] = fmaf(w8[i], bf2f((unsigned short)(u[i].x >> 16)), a1[i & 3]);
      a2[i & 3] = fmaf(w8[i], bf2f((unsigned short)(u[i].y & 0xFFFFu)), a2[i & 3]);
      a3[i & 3] = fmaf(w8[i], bf2f((unsigned short)(u[i].y >> 16)), a3[i & 3]);
    }
  }
  float dc = dinv[node];
  float s0 = ((a0[0] + a0[1]) + (a0[2] + a0[3])) * dc;
  float s1 = ((a1[0] + a1[1]) + (a1[2] + a1[3])) * dc;
  float s2 = ((a2[0] + a2[1]) + (a2[2] + a2[3])) * dc;
  float s3 = ((a3[0] + a3[1]) + (a3[2] + a3[3])) * dc;
  uint2 o;
  o.x = ((unsigned)f2bf(s1) << 16) | (unsigned)f2bf(s0);
  o.y = ((unsigned)f2bf(s3) << 16) | (unsigned)f2bf(s2);
  ((uint2*)(aggb + (size_t)node * 128))[li] = o;
}

// ---------------- GRU layer via MFMA (1024 threads, 64 nodes, 16 waves) ----------------

__global__ __launch_bounds__(1024) void gru_mfma(
    const unsigned short* __restrict__ aggb, const unsigned short* __restrict__ hdc,
    unsigned short* __restrict__ hdn, const float* __restrict__ dinv,
    const float* __restrict__ rdinv,
    const int4* __restrict__ wpk, const float* __restrict__ bih,
    const float* __restrict__ bhh, int n) {
  __shared__ unsigned short aggS[64 * 132];
  __shared__ unsigned short hS[64 * 132];
  __shared__ float partS[64 * 8];
  __shared__ float scv[64];
  __shared__ float dS[64], rS[64];
  int tid = threadIdx.x;
  int base = blockIdx.x * 64;
  int w = tid >> 6, l = tid & 63;
  int mh = w & 1, fh = w >> 1;
  int lr = l & 15, lg = l >> 4;
  int jj = fh * 16 + lr;

  if (tid < 64) {
    int gr = base + tid; if (gr > n - 1) gr = n - 1;
    dS[tid] = dinv[gr];
    rS[tid] = rdinv[gr];
  }
#pragma unroll
  for (int rep = 0; rep < 2; ++rep) {
    int idx = tid + rep * 1024;
    int row = idx >> 5, c4 = idx & 31;
    int gr = base + row; if (gr > n - 1) gr = n - 1;
    ushort4 ua = *(const ushort4*)(aggb + (size_t)gr * 128 + c4 * 4);
    ushort4 uh = *(const ushort4*)(hdc + (size_t)gr * 128 + c4 * 4);
    *(ushort4*)&aggS[row * 132 + c4 * 4] = ua;
    *(ushort4*)&hS[row * 132 + c4 * 4] = uh;
  }
  __syncthreads();

  f32x4 acc[2][6];
#pragma unroll
  for (int mt = 0; mt < 2; ++mt)
#pragma unroll
    for (int g = 0; g < 6; ++g) { acc[mt][g][0] = 0.f; acc[mt][g][1] = 0.f; acc[mt][g][2] = 0.f; acc[mt][g][3] = 0.f; }

#pragma unroll
  for (int ks = 0; ks < 4; ++ks) {
    U8 fa[2], fhh[2];
#pragma unroll
    for (int mt = 0; mt < 2; ++mt) {
      int boff = (mh * 32 + mt * 16 + lr) * 132 + ks * 32 + lg * 4;
      fa[mt].h[0] = *(const ushort4*)&aggS[boff];
      fa[mt].h[1] = *(const ushort4*)&aggS[boff + 16];
      fhh[mt].h[0] = *(const ushort4*)&hS[boff];
      fhh[mt].h[1] = *(const ushort4*)&hS[boff + 16];
    }
#pragma unroll
    for (int g = 0; g < 6; ++g) {
      U8 bw; bw.q = wpk[((ks * 6 + g) * 8 + fh) * 64 + l];
      const U8& a0 = (g < 3) ? fa[0] : fhh[0];
      const U8& a1 = (g < 3) ? fa[1] : fhh[1];
      acc[0][g] = __builtin_amdgcn_mfma_f32_16x16x32_bf16(a0.v, bw.v, acc[0][g], 0, 0, 0);
      acc[1][g] = __builtin_amdgcn_mfma_f32_16x16x32_bf16(a1.v, bw.v, acc[1][g], 0, 0, 0);
    }
  }

  float br = bih[jj], bz = bih[128 + jj], bn = bih[256 + jj];
  float cr = bhh[jj], cz = bhh[128 + jj], cn = bhh[256 + jj];
  float hn_out[2][4];
#pragma unroll
  for (int mt = 0; mt < 2; ++mt)
#pragma unroll
    for (int e = 0; e < 4; ++e) {
      int row = mh * 32 + mt * 16 + lg * 4 + e;
      float rr = rS[row];
      float ir = acc[mt][0][e], iz = acc[mt][1][e], inn = acc[mt][2][e];
      float hr = acc[mt][3][e] * rr, hz = acc[mt][4][e] * rr, hnv = acc[mt][5][e] * rr;
      float r = fast_sigmoid(ir + hr + br + cr);
      float z = fast_sigmoid(iz + hz + bz + cz);
      float ng = fast_tanh(inn + bn + r * (hnv + cn));
      float hv = bf2f(hS[row * 132 + jj]) * rr;
      float hn = (1.f - z) * ng + z * hv;
      hn_out[mt][e] = hn;
      float p = hn * hn;
      p += __shfl_xor(p, 1);
      p += __shfl_xor(p, 2);
      p += __shfl_xor(p, 4);
      p += __shfl_xor(p, 8);
      if (lr == 0) partS[row * 8 + fh] = p;
    }
  __syncthreads();
  if (tid < 64) {
    float ss = 0.f;
#pragma unroll
    for (int f = 0; f < 8; ++f) ss += partS[tid * 8 + f];
    scv[tid] = rsqrtf(fmaxf(ss, 1e-24f));
  }
  __syncthreads();

#pragma unroll
  for (int mt = 0; mt < 2; ++mt)
#pragma unroll
    for (int e = 0; e < 4; ++e) {
      int row = mh * 32 + mt * 16 + lg * 4 + e;
      aggS[row * 132 + jj] = f2bf(hn_out[mt][e] * scv[row] * dS[row]);
    }
  __syncthreads();

#pragma unroll
  for (int rep = 0; rep < 2; ++rep) {
    int idx = tid + rep * 1024;
    int row = idx >> 5, c4 = idx & 31;
    int gr = base + row;
    if (gr < n) {
      ushort4 hv4 = *(const ushort4*)&aggS[row * 132 + c4 * 4];
      *(ushort4*)(hdn + (size_t)gr * 128 + c4 * 4) = hv4;
    }
  }
}

// ---------------- decoder: 6-layer hd-max staging + MFMA + rdinv un-scale ----------------

__global__ __launch_bounds__(256) void decoder_mfma(
    const unsigned short* __restrict__ h0, const unsigned short* __restrict__ h1,
    const unsigned short* __restrict__ h2, const unsigned short* __restrict__ h3,
    const unsigned short* __restrict__ h4, const unsigned short* __restrict__ h5,
    const float* __restrict__ rdinv,
    const int4* __restrict__ wdpk, const float* __restrict__ bh,
    const float* __restrict__ Wo, const float* __restrict__ bo,
    float* __restrict__ out, int n) {
  __shared__ unsigned short zS[64 * 132];
  int tid = threadIdx.x;
  int base = blockIdx.x * 64;
  const unsigned short* hp[6] = {h0, h1, h2, h3, h4, h5};
#pragma unroll
  for (int rep = 0; rep < 8; ++rep) {
    int idx = tid + rep * 256;
    int row = idx >> 5, c4 = idx & 31;
    int gr = base + row; if (gr > n - 1) gr = n - 1;
    size_t o = (size_t)gr * 128 + c4 * 4;
    ushort4 uu[6];
#pragma unroll
    for (int li = 0; li < 6; ++li) uu[li] = *(const ushort4*)(hp[li] + o);
    ushort4 m = uu[0];
#pragma unroll
    for (int li = 1; li < 6; ++li) {
      m.x = (bf2f(uu[li].x) > bf2f(m.x)) ? uu[li].x : m.x;
      m.y = (bf2f(uu[li].y) > bf2f(m.y)) ? uu[li].y : m.y;
      m.z = (bf2f(uu[li].z) > bf2f(m.z)) ? uu[li].z : m.z;
      m.w = (bf2f(uu[li].w) > bf2f(m.w)) ? uu[li].w : m.w;
    }
    *(ushort4*)&zS[row * 132 + c4 * 4] = m;
  }
  __syncthreads();
  int w = tid >> 6, l = tid & 63;
  int lr = l & 15, lg = l >> 4;
  f32x4 acc[4];
#pragma unroll
  for (int ft = 0; ft < 4; ++ft) { acc[ft][0] = 0.f; acc[ft][1] = 0.f; acc[ft][2] = 0.f; acc[ft][3] = 0.f; }
#pragma unroll
  for (int ks = 0; ks < 4; ++ks) {
    U8 fz;
    int boff = (w * 16 + lr) * 132 + ks * 32 + lg * 4;
    fz.h[0] = *(const ushort4*)&zS[boff];
    fz.h[1] = *(const ushort4*)&zS[boff + 16];
#pragma unroll
    for (int ft = 0; ft < 4; ++ft) {
      U8 bw; bw.q = wdpk[(ks * 4 + ft) * 64 + l];
      acc[ft] = __builtin_amdgcn_mfma_f32_16x16x32_bf16(fz.v, bw.v, acc[ft], 0, 0, 0);
    }
  }
  int rowb = base + w * 16 + lg * 4;
  float rr[4];
#pragma unroll
  for (int e = 0; e < 4; ++e) {
    int gr = rowb + e; if (gr > n - 1) gr = n - 1;
    rr[e] = rdinv[gr];
  }
  float s[4] = {0.f, 0.f, 0.f, 0.f};
#pragma unroll
  for (int ft = 0; ft < 4; ++ft) {
    int j = ft * 16 + lr;
    float bj = bh[j], wj = Wo[j];
#pragma unroll
    for (int e = 0; e < 4; ++e) {
      float hid = fmaxf(fmaf(acc[ft][e], rr[e], bj), 0.f);
      s[e] = fmaf(hid, wj, s[e]);
    }
  }
#pragma unroll
  for (int e = 0; e < 4; ++e) {
    float v = s[e];
    v += __shfl_xor(v, 1);
    v += __shfl_xor(v, 2);
    v += __shfl_xor(v, 4);
    v += __shfl_xor(v, 8);
    if (lr == 0) {
      int gr = rowb + e;
      if (gr < n) out[gr] = v + bo[0];
    }
  }
}

// ---------------- launch ----------------

extern "C" void kernel_launch(void* const* d_in, const int* in_sizes, int n_in,
                              void* d_out, int out_size, void* d_ws, size_t ws_size,
                              hipStream_t stream) {
  const float* x       = (const float*)d_in[0];
  const int*   edge    = (const int*)d_in[1];
  const float* W_embed = (const float*)d_in[2];
  const float* b_embed = (const float*)d_in[3];
  const float* w_ih    = (const float*)d_in[4];
  const float* w_hh    = (const float*)d_in[5];
  const float* b_ih    = (const float*)d_in[6];
  const float* b_hh    = (const float*)d_in[7];
  const float* W_hid   = (const float*)d_in[8];
  const float* b_hid   = (const float*)d_in[9];
  const float* W_out   = (const float*)d_in[10];
  const float* b_out   = (const float*)d_in[11];
  float* out = (float*)d_out;

  const int N = in_sizes[0] / 3;       // 50000
  const int E = in_sizes[1] / 2;       // 600000
  const int NB = (N + SCAN_CHUNK - 1) / SCAN_CHUNK;

  char* ws = (char*)d_ws;
  size_t off = 0;
  auto alloc = [&](size_t bytes) -> void* {
    void* p = ws + off;
    off = (off + bytes + 511) & ~(size_t)511;
    return p;
  };
  int*   deg     = (int*)alloc((size_t)N * 4);
  float* dinv    = (float*)alloc((size_t)N * 4);
  float* rdinv   = (float*)alloc((size_t)N * 4);
  int*   row_ptr = (int*)alloc((size_t)(N + 1) * 4);
  int*   cursor  = (int*)alloc((size_t)N * 4);
  int*   bsum    = (int*)alloc((size_t)NB * 4);
  int*   boff    = (int*)alloc((size_t)NB * 4);
  int*   srcv    = (int*)alloc((size_t)(E + 8) * 4);
  unsigned short* wpack  = (unsigned short*)alloc((size_t)491520 * 2);
  unsigned short* wdpack = (unsigned short*)alloc((size_t)8192 * 2);
  unsigned short* aggb   = (unsigned short*)alloc((size_t)N * 128 * 2);
  unsigned short* hbs[6];
  for (int i = 0; i < 6; ++i) hbs[i] = (unsigned short*)alloc((size_t)N * 128 * 2);

  const int* erow = edge;
  const int* ecol = edge + E;

  hipMemsetAsync(deg, 0, (size_t)N * 4, stream);
  count_deg<<<(E + NTHREADS - 1) / NTHREADS, NTHREADS, 0, stream>>>(ecol, deg, E);
  block_reduce<<<NB, NTHREADS, 0, stream>>>(deg, bsum, dinv, rdinv, N);
  scan_partials<<<1, 64, 0, stream>>>(bsum, boff, row_ptr + N, NB);
  scan_final<<<NB, NTHREADS, 0, stream>>>(deg, boff, row_ptr, cursor, N);
  scatter_edges<<<(E + NTHREADS - 1) / NTHREADS, NTHREADS, 0, stream>>>(erow, ecol, cursor, srcv, E);

  pack_all<<<(491520 + 8192 + NTHREADS - 1) / NTHREADS, NTHREADS, 0, stream>>>(
      w_ih, w_hh, W_hid, wpack, wdpack);

  encoder<<<(N + 3) / 4, NTHREADS, 0, stream>>>(x, W_embed, b_embed, dinv, hbs[0], N);

  for (int l = 0; l < 5; ++l) {
    aggregate<<<(N + 7) / 8, NTHREADS, 0, stream>>>(row_ptr, srcv, dinv, hbs[l], aggb, N);
    gru_mfma<<<(N + 63) / 64, 1024, 0, stream>>>(
        aggb, hbs[l], hbs[l + 1], dinv, rdinv,
        (const int4*)(wpack + (size_t)l * 98304),
        b_ih + (size_t)l * 384, b_hh + (size_t)l * 384, N);
  }

  decoder_mfma<<<(N + 63) / 64, NTHREADS, 0, stream>>>(
      hbs[0], hbs[1], hbs[2], hbs[3], hbs[4], hbs[5], rdinv,
      (const int4*)wdpack, b_hid, W_out, b_out, out, N);
}